// Round 10
// baseline (298.036 us; speedup 1.0000x reference)
//
#include <hip/hip_runtime.h>

// DecayModel: out[b,i,h] = (fwd[i] + bwd[i]) / norm[i], decay = 0.5
//   fwd[i] = sum_{k<=i} 0.5^{i-k} x[k],  bwd[i] = sum_{k>=i} 0.5^{k-i} x[k]
//   norm[i] = 4 - 2^{-i} - 2^{-(S-1-i)}   (== 4.0f exactly for interior i)
//
// R15 -> R16: stop fighting the serial chain; double the waves.
// R15 (40 asm-volatile loads) STILL showed VGPR=48: hipcc interleaves the
// consumers between the asm loads (conservative asm-def waits) and rebuilds
// the serial load->use chain; sched_barrier and waitcnt asm are both
// ineffective (R12/R13/R15). Conclusion: per-wave load ILP is not
// controllable from HIP source here. Re-model with serial chains as given:
//   per-block time = 40 x L_eff (L_eff ~ 1260 cyc queued L2/L3 latency)
//   CU throughput  = waves/CU x bytes-per-step / L_eff
// (history check: R5 v4f@44%occ = 3.4 TB/s vs R11 v2f@46% = 2.4 TB/s ->
// bytes/step scaling real; R7-vs-R11 flat BW consistent too.)
// Lever 1 (this round): waves. VGPR=48 <= 64 qualifies for 32 waves/CU;
// launch_bounds (256,4) was only asking for 16. Change to (256,8):
// 8 blocks/CU, grid 4096 = exactly 2 generations. NOTHING else changed
// from the verified R11 structure -> clean single-variable A/B.
// Predict: occupancy 46->~90%, BW 2.4->~4.8 TB/s, dur 84->~42us.
// If occupancy doubles and BW is flat: concurrency model falsified ->
// pivot to v4f chain steps (bytes/step axis).

constexpr int B = 16;
constexpr int S = 2048;
constexpr int H = 1024;
constexpr int H2 = H / 2;        // 512 float2 per row
constexpr int C = 16;            // tile rows per block
constexpr int K = 12;            // halo taps: 0.5^13 * 6sigma ~ 7e-4 << tol
constexpr int THREADS = 256;     // 4 waves; each thread owns one float2 col
constexpr int CG = H2 / THREADS; // 2 column groups per row
constexpr int NCH = S / C;       // 128 chunks
constexpr int NBLK = B * NCH * CG;  // 4096 blocks -> 8 resident per CU
constexpr int NXCD = 8;

typedef float v2f __attribute__((ext_vector_type(2)));

__global__ __launch_bounds__(THREADS, 8) void decay_kernel(
    const v2f* __restrict__ x, v2f* __restrict__ out) {
    // Bijective XCD swizzle (NBLK % 8 == 0): each XCD owns 2 whole batches;
    // chunk-neighbors (sharing 12-row halos) stay in one XCD's L2.
    const int bid = blockIdx.x;
    const int swz = (bid & (NXCD - 1)) * (NBLK / NXCD) + (bid >> 3);
    const int cg = swz & (CG - 1);
    const int chunk = (swz >> 1) & (NCH - 1);
    const int b = swz >> 8;
    const int s0 = chunk * C;

    const size_t colBase =
        (size_t)b * S * H2 + (size_t)cg * THREADS + threadIdx.x;
    const v2f* __restrict__ xp = x + colBase;  // xp[s*H2] = x[b, s, col]
    v2f* __restrict__ op = out + colBase;

    // ---- 40 row loads (compiler will serialize; TLP hides it) ----
    v2f xl[K], xa[C], xr[K];
#pragma unroll
    for (int r = 0; r < K; ++r) {
        const int s = s0 - K + r;
        xl[r] = xp[(size_t)(s < 0 ? 0 : s) * H2];
    }
#pragma unroll
    for (int r = 0; r < C; ++r) xa[r] = xp[(size_t)(s0 + r) * H2];
#pragma unroll
    for (int r = 0; r < K; ++r) {
        const int s = s0 + C + r;
        xr[r] = xp[(size_t)(s > S - 1 ? S - 1 : s) * H2];
    }

    // zero out-of-range halo rows (wave-uniform; only first/last chunks)
    if (chunk == 0) {
#pragma unroll
        for (int r = 0; r < K; ++r) xl[r] = (v2f)0.0f;
    }
    if (chunk == NCH - 1) {
#pragma unroll
        for (int r = 0; r < K; ++r) xr[r] = (v2f)0.0f;
    }

    // ---- forward recurrence (K-tap truncated carry-in, exact in tile) ----
    v2f facc = (v2f)0.0f;
#pragma unroll
    for (int r = 0; r < K; ++r) facc = 0.5f * facc + xl[r];
    const v2f fm1 = facc;  // fwd[s0-1]
#pragma unroll
    for (int r = 0; r < C; ++r) {
        facc = 0.5f * facc + xa[r];
        xa[r] = facc;  // buffer now holds fwd
    }

    // ---- backward recurrence + combine + store ----
    v2f bacc = (v2f)0.0f;
#pragma unroll
    for (int r = K - 1; r >= 0; --r) bacc = 0.5f * bacc + xr[r];

    const bool interior = (s0 >= 32) && (s0 + C <= S - 32);
#pragma unroll
    for (int r = C - 1; r >= 0; --r) {
        const v2f f = xa[r];                       // fwd[i]
        const v2f fp = (r > 0) ? xa[r - 1] : fm1;  // fwd[i-1]
        bacc = 0.5f * bacc + (f - 0.5f * fp);      // recover x[i], extend bwd
        const int i = s0 + r;
        float rn = 0.25f;  // norm == 4.0f exactly for interior rows
        if (!interior) {
            rn = 1.0f / (4.0f - exp2f((float)(-i)) -
                         exp2f((float)(i - (S - 1))));
        }
        __builtin_nontemporal_store((f + bacc) * rn, op + (size_t)i * H2);
    }
}

extern "C" void kernel_launch(void* const* d_in, const int* in_sizes, int n_in,
                              void* d_out, int out_size, void* d_ws,
                              size_t ws_size, hipStream_t stream) {
    const v2f* x = (const v2f*)d_in[0];
    v2f* out = (v2f*)d_out;
    decay_kernel<<<dim3(NBLK), THREADS, 0, stream>>>(x, out);
}

// Round 12
// 237.648 us; speedup vs baseline: 1.2541x; 1.2541x over previous
//
#include <hip/hip_runtime.h>
#include <stdint.h>

// DecayModel: out[b,i,h] = (fwd[i] + bwd[i]) / norm[i], decay = 0.5
//   fwd[i] = sum_{k<=i} 0.5^{i-k} x[k],  bwd[i] = sum_{k>=i} 0.5^{k-i} x[k]
//   norm[i] = 4 - 2^{-i} - 2^{-(S-1-i)}   (== 4.0f exactly for interior i)
//
// R17 resubmit (R18): broker timeout, no signal -- experiment unchanged.
// Contiguous-stream DMA pipeline (tests BOTH residual theories).
// History: R5/R7/R9/R11/R13/R15/R16 all plateau at ~84-93us, 2.3-3.4 TB/s.
//  Theory A (depth-1 chains): hipcc always serializes reg-destination loads
//   (R12/R13/R15 proved it can't be fought). global_load_lds has NO dest
//   reg -> nothing to sink; DMA instrs issue as a true burst.
//  Theory B (4KB-stride pathology): every prior design had each wave read a
//   512B column slab striding exactly 4096B -> frozen low addr bits hammer
//   a channel subset. This kernel's wave streams CONTIGUOUS rows instead.
// Structure: block = full row (256 thr x v4f = 4KB); chunk C=64 rows walked
// in W=4-row subtiles; 4-buffer LDS ring (64KB); wave w DMAs row w of each
// subtile (4x1KB contiguous; block subtile = contiguous 16KB). Scan reads
// columns via ds_read_b128 (conflict-free: 16B/lane consecutive).
// Ledger (fixes R9): per iter per wave = 4 loads + 4 stores.
//   top of iter m: outstanding = [loads(m-1):4, stores(m-1):4]
//   vmcnt(4) drains exactly loads(m-1), keeps stores in flight (never 0
//   except iter 0 prologue). Prefetch->use slack = 1 full iter (~3k cyc).
// Raw s_barrier (m201 pattern), K=8 taps (err ~6e-4 << 6.4e-2 tol).
// Predict: VGPR ~60, occupancy ~25%, dur 45-60us. If ~84us again: both
// theories falsified -> this op's wall on this toolchain (disasm next).

constexpr int B = 16;
constexpr int S = 2048;
constexpr int HV = 256;          // v4f per row (1024 floats)
constexpr int C = 64;            // chunk rows per block
constexpr int W = 4;             // subtile rows (== waves per block)
constexpr int NT = C / W;        // 16 iterations
constexpr int THREADS = 256;
constexpr int NCHUNK = S / C;    // 32
constexpr int NBLK = B * NCHUNK; // 512 blocks -> 2 per CU
constexpr int NXCD = 8;

typedef float v4f __attribute__((ext_vector_type(4)));

__device__ __forceinline__ void gload16(const v4f* g, v4f* l) {
    // HBM -> LDS direct, 16B/lane; LDS dest = wave-uniform base + lane*16.
    __builtin_amdgcn_global_load_lds(
        (const __attribute__((address_space(1))) uint32_t*)g,
        (__attribute__((address_space(3))) uint32_t*)l, 16, 0, 0);
}

// Stage one 4-row subtile: wave w DMAs global row (row0+w, clamped) into
// LDS row w of buf -- 4 x 1KB instructions, contiguous 4KB per wave.
__device__ __forceinline__ void stage(const v4f* xb, int row0,
                                      v4f (*buf)[HV], int w, int lane) {
    int g = row0 + w;
    g = g < 0 ? 0 : (g > S - 1 ? S - 1 : g);
    const v4f* src = xb + (size_t)g * HV + lane;
#pragma unroll
    for (int j = 0; j < 4; ++j) gload16(src + j * 64, &buf[w][j * 64]);
}

__global__ __launch_bounds__(THREADS, 2) void decay_kernel(
    const v4f* __restrict__ x, v4f* __restrict__ out) {
    __shared__ v4f lds[4][W][HV];  // 4 bufs x 4 rows x 4KB = 64 KiB

    // Bijective XCD swizzle (512 % 8 == 0): each XCD gets 64 consecutive
    // work items = 2 whole batches; chunk-neighbors share halo rows in L2.
    const int bid = blockIdx.x;
    const int swz = (bid & (NXCD - 1)) * (NBLK / NXCD) + (bid >> 3);
    const int cc = swz & (NCHUNK - 1);
    const int b = swz / NCHUNK;
    const int s0 = cc * C;
    const bool edge = (cc == 0) | (cc == NCHUNK - 1);

    const int tid = threadIdx.x;
    const int w = tid >> 6;
    const int lane = tid & 63;
    const v4f* __restrict__ xb = x + (size_t)b * S * HV;
    v4f* __restrict__ ob = out + (size_t)b * S * HV + tid;

    // ---- prologue: halo subs -2,-1 -> bufs 2,3; subs 0,1 -> bufs 0,1 ----
    stage(xb, s0 - 8, lds[2], w, lane);
    stage(xb, s0 - 4, lds[3], w, lane);
    stage(xb, s0, lds[0], w, lane);
    stage(xb, s0 + 4, lds[1], w, lane);
    asm volatile("s_waitcnt vmcnt(8)" ::: "memory");  // halo done; 0,1 fly
    __builtin_amdgcn_s_barrier();

    // fwd carry-in: 8-tap truncated scan over the halo (zero for chunk 0)
    v4f facc = (v4f)0.0f;
    if (cc > 0) {
#pragma unroll
        for (int r = 0; r < W; ++r) facc = 0.5f * facc + lds[2][r][tid];
#pragma unroll
        for (int r = 0; r < W; ++r) facc = 0.5f * facc + lds[3][r][tid];
    }
    // pin the halo reads + carry chain before buf2 is overwritten
    asm volatile("s_waitcnt lgkmcnt(0)" ::: "memory");
    __builtin_amdgcn_sched_barrier(0);
    __builtin_amdgcn_s_barrier();
    stage(xb, s0 + 8, lds[2], w, lane);  // sub 2 (halo consumed)

    // ---- main loop: NT subtiles ----
    for (int m = 0; m < NT; ++m) {
        // drain loads(m-1) (which filled buf (m+2)); keep stores in flight.
        if (m == 0)
            asm volatile("s_waitcnt vmcnt(0)" ::: "memory");  // prologue only
        else
            asm volatile("s_waitcnt vmcnt(4)" ::: "memory");
        __builtin_amdgcn_s_barrier();

        // prefetch subtile m+3 (subs NT, NT+1 = right halo; clamped rows)
        if (m + 3 <= NT + 1)
            stage(xb, s0 + (m + 3) * W, lds[(m + 3) & 3], w, lane);

        // ---- forward recurrence over subtile m (exact within chunk) ----
        const v4f fprev = facc;
        v4f f[W];
#pragma unroll
        for (int r = 0; r < W; ++r) {
            facc = 0.5f * facc + lds[m & 3][r][tid];
            f[r] = facc;
        }

        // ---- backward 8-tap lookahead from subs m+1, m+2 ----
        v4f bacc = (v4f)0.0f;
        const int la0 = s0 + (m + 1) * W;
#pragma unroll
        for (int j = 2 * W - 1; j >= 0; --j) {
            v4f t = (j < W) ? lds[(m + 1) & 3][j][tid]
                            : lds[(m + 2) & 3][j - W][tid];
            if (la0 + j >= S) t = (v4f)0.0f;  // rows past end contribute 0
            bacc = 0.5f * bacc + t;
        }

        // ---- backward march + combine + store ----
#pragma unroll
        for (int r = W - 1; r >= 0; --r) {
            const v4f fr = f[r];
            const v4f fm_ = r ? f[r - 1] : fprev;
            bacc = 0.5f * bacc + (fr - 0.5f * fm_);  // recover x, extend bwd
            const int i = s0 + m * W + r;
            float rn = 0.25f;  // norm == 4.0f exactly for interior rows
            if (edge)
                rn = 1.0f / (4.0f - exp2f((float)(-i)) -
                             exp2f((float)(i - (S - 1))));
            __builtin_nontemporal_store((fr + bacc) * rn,
                                        ob + (size_t)i * HV);
        }
    }
}

extern "C" void kernel_launch(void* const* d_in, const int* in_sizes, int n_in,
                              void* d_out, int out_size, void* d_ws,
                              size_t ws_size, hipStream_t stream) {
    const v4f* x = (const v4f*)d_in[0];
    v4f* out = (v4f*)d_out;
    decay_kernel<<<dim3(NBLK), THREADS, 0, stream>>>(x, out);
}